// Round 11
// baseline (94.862 us; speedup 1.0000x reference)
//
#include <hip/hip_runtime.h>
#include <hip/hip_bf16.h>
#include <math.h>

#define S_LEN 2048
#define DM    1024
#define NH    16
#define DH    64
#define CHUNK 64
#define NCH   (S_LEN / CHUNK)          // 32
#define ST_STRIDE (DH * DH + DH)       // 4160 floats per (head,chunk) state

typedef __attribute__((ext_vector_type(8))) short bf16x8;   // 8 bf16 in 4 VGPRs
typedef __attribute__((ext_vector_type(4))) float f32x4;

__device__ __forceinline__ float softplus_f(float x) {
    return (x > 20.0f) ? x : log1pf(expf(x));
}

__device__ __forceinline__ ushort bf16r(float f) {   // round-to-nearest-even f32 -> bf16
    union { float f; unsigned int u; } c; c.f = f;
    unsigned int u = c.u;
    u = (u + 0x7FFFu + ((u >> 16) & 1u)) >> 16;
    return (ushort)u;
}

__device__ __forceinline__ float b2f(ushort u) {     // bf16 -> f32 (shift)
    union { unsigned int i; float f; } c; c.i = ((unsigned int)u) << 16;
    return c.f;
}

// ---------------- fused cast: x (2 slabs) + 4 weights, one launch ----------------
__global__ __launch_bounds__(256)
void cast_all_kernel(const float* __restrict__ x,
                     const float* __restrict__ Wq, const float* __restrict__ Wk,
                     const float* __restrict__ Wv, const float* __restrict__ Wo,
                     ushort* __restrict__ x_bf, ushort* __restrict__ w_bf)
{
    const int y = blockIdx.y;          // 0,1: x halves; 2..5: Wq,Wk,Wv,Wo
    const float* src;
    ushort* dst;
    if (y < 2) { src = x + (size_t)y * (DM * DM);  dst = x_bf + (size_t)y * (DM * DM); }
    else {
        const float* ws[4] = {Wq, Wk, Wv, Wo};
        src = ws[y - 2];  dst = w_bf + (size_t)(y - 2) * (DM * DM);
    }
    const int i = (blockIdx.x * 256 + threadIdx.x) * 4;
    const float4 v = *(const float4*)(src + i);
    ushort4 o; o.x = bf16r(v.x); o.y = bf16r(v.y); o.z = bf16r(v.z); o.w = bf16r(v.w);
    *(ushort4*)(dst + i) = o;
}

// ============ QKV GEMM: BM=64 x BN=128, BK=64, 768 blocks (3/CU) — R9-proven, bf16 out ======
__global__ __launch_bounds__(256)
void qkv_gemm_kernel(const ushort* __restrict__ Xb, const ushort* __restrict__ Wqkv,
                     const float* __restrict__ bq, const float* __restrict__ bk,
                     const float* __restrict__ bv,
                     const float* __restrict__ beta,
                     ushort* __restrict__ qkv /* q|k|v contiguous, bf16 head layout */)
{
    __shared__ ushort Als[64 * 64];    // 8 KB
    __shared__ ushort Bls[128 * 64];   // 16 KB

    const int b = blockIdx.x;
    const int logical = (b & 7) * 96 + (b >> 3);      // XCD-bijective (768%8==0)
    const int mb = logical & 31, nb = logical >> 5;   // m-fastest within XCD
    const int m0 = mb * 64, n0 = nb * 128;
    const int z  = nb >> 3;                           // 0:q 1:k 2:v
    const int nz0 = (nb & 7) * 128;
    const float* bias = (z == 0) ? bq : (z == 1) ? bk : bv;

    const int t = threadIdx.x, w = t >> 6, l = t & 63;
    const int wr = w >> 1, wc = w & 1;                // 2x2 wave grid
    const int r8 = l >> 3;
    const int scol = ((l & 7) ^ r8) * 8;              // inverse-swizzled source col (elems)
    const int frow = l & 15, kq = l >> 4;

    f32x4 acc[2][4];
#pragma unroll
    for (int mi = 0; mi < 2; ++mi)
#pragma unroll
        for (int ni = 0; ni < 4; ++ni) acc[mi][ni] = (f32x4){0.f, 0.f, 0.f, 0.f};

    for (int kt = 0; kt < DM; kt += 64) {
#pragma unroll
        for (int k2 = 0; k2 < 6; ++k2) {
            const int idx = w + 4 * k2;
            if (idx < 8) {
                __builtin_amdgcn_global_load_lds(
                    (const __attribute__((address_space(1))) void*)(Xb + (size_t)(m0 + idx * 8 + r8) * DM + kt + scol),
                    (__attribute__((address_space(3))) void*)(Als + idx * 512), 16, 0, 0);
            } else {
                const int ib = idx - 8;
                __builtin_amdgcn_global_load_lds(
                    (const __attribute__((address_space(1))) void*)(Wqkv + (size_t)(n0 + ib * 8 + r8) * DM + kt + scol),
                    (__attribute__((address_space(3))) void*)(Bls + ib * 512), 16, 0, 0);
            }
        }
        __syncthreads();

#pragma unroll
        for (int ks = 0; ks < 2; ++ks) {
            bf16x8 af[2], bf[4];
#pragma unroll
            for (int mi = 0; mi < 2; ++mi) {
                const int rr = wr * 32 + mi * 16 + frow;
                af[mi] = *(const bf16x8*)&Als[rr * 64 + (((kq + 4 * ks) ^ (rr & 7)) << 3)];
            }
#pragma unroll
            for (int ni = 0; ni < 4; ++ni) {
                const int rr = wc * 64 + ni * 16 + frow;
                bf[ni] = *(const bf16x8*)&Bls[rr * 64 + (((kq + 4 * ks) ^ (rr & 7)) << 3)];
            }
#pragma unroll
            for (int mi = 0; mi < 2; ++mi)
#pragma unroll
                for (int ni = 0; ni < 4; ++ni)
                    acc[mi][ni] = __builtin_amdgcn_mfma_f32_16x16x32_bf16(af[mi], bf[ni], acc[mi][ni], 0, 0, 0);
        }
        __syncthreads();
    }

    ushort* outz = qkv + (size_t)z * (NH * S_LEN * DH);
#pragma unroll
    for (int ni = 0; ni < 4; ++ni) {
        const int col = nz0 + wc * 64 + ni * 16 + (l & 15);
        const int h = col >> 6, d = col & 63;
        const float bcol = bias[col];
        const float inv = (z < 2) ? (1.0f / (8.0f * expf(beta[h]))) : 1.0f;
#pragma unroll
        for (int mi = 0; mi < 2; ++mi) {
            const int rbase = m0 + wr * 32 + mi * 16 + (l >> 4) * 4;
#pragma unroll
            for (int r = 0; r < 4; ++r) {
                float v = acc[mi][ni][r] + bcol;
                if (z < 2) v = softplus_f(v * inv);
                outz[((size_t)h * S_LEN + rbase + r) * DH + d] = bf16r(v);
            }
        }
    }
}

// ============ O projection: LDS-staged, BK=64, 512 blocks (2/CU) ============
__global__ __launch_bounds__(256)
void o_gemm_kernel(const ushort* __restrict__ Ab, const ushort* __restrict__ Wob,
                   const float* __restrict__ bo, float* __restrict__ out)
{
    __shared__ ushort Als[64 * 64];    // 8 KB
    __shared__ ushort Bls[64 * 64];    // 8 KB

    const int b = blockIdx.x;
    const int logical = (b & 7) * 64 + (b >> 3);      // XCD-bijective (512%8==0)
    const int mb = logical & 31, nb = logical >> 5;   // 32 x 16 tiles
    const int m0 = mb * 64, n0 = nb * 64;

    const int t = threadIdx.x, w = t >> 6, l = t & 63;
    const int wr = w >> 1, wc = w & 1;
    const int r8 = l >> 3;
    const int scol = ((l & 7) ^ r8) * 8;
    const int frow = l & 15, kq = l >> 4;

    f32x4 acc[2][2];
#pragma unroll
    for (int mi = 0; mi < 2; ++mi)
#pragma unroll
        for (int ni = 0; ni < 2; ++ni) acc[mi][ni] = (f32x4){0.f, 0.f, 0.f, 0.f};

    for (int kt = 0; kt < DM; kt += 64) {
#pragma unroll
        for (int k2 = 0; k2 < 4; ++k2) {
            const int idx = w + 4 * k2;                // 0..15
            if (idx < 8) {
                __builtin_amdgcn_global_load_lds(
                    (const __attribute__((address_space(1))) void*)(Ab + (size_t)(m0 + idx * 8 + r8) * DM + kt + scol),
                    (__attribute__((address_space(3))) void*)(Als + idx * 512), 16, 0, 0);
            } else {
                const int ib = idx - 8;
                __builtin_amdgcn_global_load_lds(
                    (const __attribute__((address_space(1))) void*)(Wob + (size_t)(n0 + ib * 8 + r8) * DM + kt + scol),
                    (__attribute__((address_space(3))) void*)(Bls + ib * 512), 16, 0, 0);
            }
        }
        __syncthreads();

#pragma unroll
        for (int ks = 0; ks < 2; ++ks) {
            bf16x8 af[2], bf[2];
#pragma unroll
            for (int mi = 0; mi < 2; ++mi) {
                const int rr = wr * 32 + mi * 16 + frow;
                af[mi] = *(const bf16x8*)&Als[rr * 64 + (((kq + 4 * ks) ^ (rr & 7)) << 3)];
            }
#pragma unroll
            for (int ni = 0; ni < 2; ++ni) {
                const int rr = wc * 32 + ni * 16 + frow;
                bf[ni] = *(const bf16x8*)&Bls[rr * 64 + (((kq + 4 * ks) ^ (rr & 7)) << 3)];
            }
#pragma unroll
            for (int mi = 0; mi < 2; ++mi)
#pragma unroll
                for (int ni = 0; ni < 2; ++ni)
                    acc[mi][ni] = __builtin_amdgcn_mfma_f32_16x16x32_bf16(af[mi], bf[ni], acc[mi][ni], 0, 0, 0);
        }
        __syncthreads();
    }

#pragma unroll
    for (int ni = 0; ni < 2; ++ni) {
        const int col = n0 + wc * 32 + ni * 16 + (l & 15);
        const float bcol = bo[col];
#pragma unroll
        for (int mi = 0; mi < 2; ++mi) {
            const int rbase = m0 + wr * 32 + mi * 16 + (l >> 4) * 4;
#pragma unroll
            for (int r = 0; r < 4; ++r)
                out[(size_t)(rbase + r) * DM + col] = acc[mi][ni][r] + bcol;
        }
    }
}

// ---------------- Pass B: per (head, chunk) state (bf16 k/v inputs) ----------------
__global__ __launch_bounds__(256)
void chunk_state_kernel(const ushort* __restrict__ k_ws, const ushort* __restrict__ v_ws,
                        float* __restrict__ st)
{
    __shared__ float Ks[64][64];
    __shared__ float Vs[64][64];
    const int c = blockIdx.x, h = blockIdx.y;
    const int t = threadIdx.x;
    const ushort* Kg = k_ws + ((size_t)h * S_LEN + c * CHUNK) * DH;
    const ushort* Vg = v_ws + ((size_t)h * S_LEN + c * CHUNK) * DH;
#pragma unroll
    for (int u = 0; u < 4; ++u) {
        int f = u * 256 + t;
        const ushort4 k4 = ((const ushort4*)Kg)[f];
        const ushort4 v4 = ((const ushort4*)Vg)[f];
        float* kp = &Ks[0][0] + f * 4;
        float* vp = &Vs[0][0] + f * 4;
        kp[0] = b2f(k4.x); kp[1] = b2f(k4.y); kp[2] = b2f(k4.z); kp[3] = b2f(k4.w);
        vp[0] = b2f(v4.x); vp[1] = b2f(v4.y); vp[2] = b2f(v4.z); vp[3] = b2f(v4.w);
    }
    __syncthreads();

    const int tx = t & 15, ty = t >> 4;
    float acc[4][4];
#pragma unroll
    for (int i = 0; i < 4; ++i)
#pragma unroll
        for (int j = 0; j < 4; ++j) acc[i][j] = 0.0f;

    for (int s = 0; s < 64; ++s) {
        const float4 kd = *(const float4*)&Ks[s][ty * 4];
        const float4 ve = *(const float4*)&Vs[s][tx * 4];
        const float kv[4] = {kd.x, kd.y, kd.z, kd.w};
        const float vv[4] = {ve.x, ve.y, ve.z, ve.w};
#pragma unroll
        for (int i = 0; i < 4; ++i)
#pragma unroll
            for (int j = 0; j < 4; ++j) acc[i][j] += kv[i] * vv[j];
    }
    float* base = st + (size_t)(h * NCH + c) * ST_STRIDE;
#pragma unroll
    for (int i = 0; i < 4; ++i) {
        float4 o; o.x = acc[i][0]; o.y = acc[i][1]; o.z = acc[i][2]; o.w = acc[i][3];
        *(float4*)(base + (ty * 4 + i) * 64 + tx * 4) = o;
    }
    if (t < 64) {
        float s = 0.0f;
        for (int j = 0; j < 64; ++j) s += Ks[j][t];
        base[DH * DH + t] = s;
    }
}

// -------- Pass C: in-place exclusive prefix scan; ALSO emits bf16 TRANSPOSED prefix --------
// st fp32 stays (k1p precision for the denominator); pfxT[(h*NCH+c)*4160 + e*64 + d] bf16
// holds KVp^T (rows = e, k = d contiguous) -> direct MFMA B-operand in attn_out.
__global__ __launch_bounds__(64)
void scan_kernel(float* __restrict__ st, ushort* __restrict__ pfxT)
{
    const int h = blockIdx.y;
    const int e = blockIdx.x * 64 + threadIdx.x;   // [0, ST_STRIDE)
    float* p = st + (size_t)h * NCH * ST_STRIDE + e;
    int tidx;
    if (e < DH * DH) { const int d = e >> 6, eo = e & 63; tidx = eo * 64 + d; }
    else tidx = e;                                  // k1 tail (unused by MFMA path)
    ushort* pt = pfxT + (size_t)h * NCH * ST_STRIDE;
    float acc = 0.0f;
    for (int c = 0; c < NCH; ++c) {
        const float v = p[(size_t)c * ST_STRIDE];
        p[(size_t)c * ST_STRIDE] = acc;             // exclusive prefix (same-thread RAW safe)
        pt[(size_t)c * ST_STRIDE + tidx] = bf16r(acc);
        acc += v;
    }
}

// ---------------- Pass D: per (head, chunk) output — MFMA version ----------------
// S = Q K^T (frags straight from global bf16; fp32 MFMA accum = no precision loss vs VALU).
// mask+rowsum in-register; P -> bf16 -> swizzled LDS (intra-wave rows only).
// O = P.V (Vt staged transposed+swizzled) + Q.KVp^T (pfxT frags from global);
// den = Q.k1p (fp32 from st) + rowsum.  LDS ~17KB.
// Swizzle = the R4-R10 zero-conflict pattern: granule_phys = granule_log ^ (row&7).
__global__ __launch_bounds__(256)
void attn_out_kernel(const ushort* __restrict__ q_ws, const ushort* __restrict__ k_ws,
                     const ushort* __restrict__ v_ws, const float* __restrict__ pfx,
                     const ushort* __restrict__ pfxT, ushort* __restrict__ out_pre)
{
    __shared__ ushort Vt[64 * 64];     // [e][s] swizzled, 8 KB
    __shared__ ushort Ps[64 * 64];     // [i][j] swizzled, 8 KB
    __shared__ float denA[64];
    __shared__ float rsA[64];

    const int c = blockIdx.x, h = blockIdx.y;
    const int t = threadIdx.x, w = t >> 6, l = t & 63;
    const int fr = l & 15, fg = l >> 4;
    const int iw0 = w * 16;                         // wave's output row stripe
    const size_t cbase = ((size_t)h * S_LEN + c * CHUNK) * DH;
    const ushort* Qg = q_ws + cbase;
    const ushort* Kg = k_ws + cbase;
    const ushort* Vg = v_ws + cbase;
    const float*  pb = pfx  + (size_t)(h * NCH + c) * ST_STRIDE;
    const ushort* pT = pfxT + (size_t)(h * NCH + c) * ST_STRIDE;

    // ---- stage Vt = V^T (bf16, swizzled) : thread t handles V row s, 16-e block ----
    {
        const int s = t >> 2, e0 = (t & 3) * 16;
        ushort vv[16];
        *(ushort4*)(vv + 0)  = *(const ushort4*)(Vg + s * 64 + e0);
        *(ushort4*)(vv + 4)  = *(const ushort4*)(Vg + s * 64 + e0 + 4);
        *(ushort4*)(vv + 8)  = *(const ushort4*)(Vg + s * 64 + e0 + 8);
        *(ushort4*)(vv + 12) = *(const ushort4*)(Vg + s * 64 + e0 + 12);
#pragma unroll
        for (int ee = 0; ee < 16; ++ee) {
            const int e = e0 + ee;
            Vt[e * 64 + ((((s >> 3) ^ (e & 7)) << 3) | (s & 7))] = vv[ee];
        }
    }

    // ---- Q/K fragments from global; S = Q K^T ----
    bf16x8 qf[2], kf0, kf1;
#pragma unroll
    for (int kh = 0; kh < 2; ++kh)
        qf[kh] = *(const bf16x8*)(Qg + (iw0 + fr) * 64 + kh * 32 + fg * 8);

    f32x4 sacc[4];
#pragma unroll
    for (int jn = 0; jn < 4; ++jn) sacc[jn] = (f32x4){0.f, 0.f, 0.f, 0.f};
#pragma unroll
    for (int jn = 0; jn < 4; ++jn) {
        kf0 = *(const bf16x8*)(Kg + (jn * 16 + fr) * 64 + fg * 8);
        kf1 = *(const bf16x8*)(Kg + (jn * 16 + fr) * 64 + 32 + fg * 8);
        sacc[jn] = __builtin_amdgcn_mfma_f32_16x16x32_bf16(qf[0], kf0, sacc[jn], 0, 0, 0);
        sacc[jn] = __builtin_amdgcn_mfma_f32_16x16x32_bf16(qf[1], kf1, sacc[jn], 0, 0, 0);
    }

    // ---- mask, rowsum, P -> bf16 swizzled LDS ----
    float pr0 = 0.f, pr1 = 0.f, pr2 = 0.f, pr3 = 0.f;
#pragma unroll
    for (int jn = 0; jn < 4; ++jn) {
        const int j = jn * 16 + fr;
        const int gj = (jn * 2 + (fr >> 3));        // granule of j
#pragma unroll
        for (int r = 0; r < 4; ++r) {
            const int i = iw0 + fg * 4 + r;
            const float v = (j <= i) ? sacc[jn][r] : 0.0f;
            if (r == 0) pr0 += v; else if (r == 1) pr1 += v;
            else if (r == 2) pr2 += v; else pr3 += v;
            Ps[i * 64 + (((gj ^ (i & 7)) << 3) | (fr & 7))] = bf16r(v);
        }
    }
#pragma unroll
    for (int d = 1; d < 16; d <<= 1) {
        pr0 += __shfl_xor(pr0, d, 64);
        pr1 += __shfl_xor(pr1, d, 64);
        pr2 += __shfl_xor(pr2, d, 64);
        pr3 += __shfl_xor(pr3, d, 64);
    }
    if (fr == 0)      rsA[iw0 + fg * 4 + 0] = pr0;
    else if (fr == 1) rsA[iw0 + fg * 4 + 1] = pr1;
    else if (fr == 2) rsA[iw0 + fg * 4 + 2] = pr2;
    else if (fr == 3) rsA[iw0 + fg * 4 + 3] = pr3;

    // ---- den_inter = Q . k1p (fp32) ----
    float den = 0.f;
#pragma unroll
    for (int kh = 0; kh < 2; ++kh)
#pragma unroll
        for (int jj = 0; jj < 8; ++jj)
            den += b2f((ushort)qf[kh][jj]) * pb[DH * DH + kh * 32 + fg * 8 + jj];
    den += __shfl_xor(den, 16, 64);
    den += __shfl_xor(den, 32, 64);
    if (l < 16) denA[iw0 + l] = den;

    __syncthreads();   // Vt / Ps / denA / rsA complete

    // ---- O = P.V + Q.KVp^T ----
    bf16x8 paf[2];
#pragma unroll
    for (int kh = 0; kh < 2; ++kh)
        paf[kh] = *(const bf16x8*)&Ps[(iw0 + fr) * 64 + ((((kh * 4 + fg) ^ (fr & 7))) << 3)];

    f32x4 oacc[4];
#pragma unroll
    for (int jn = 0; jn < 4; ++jn) oacc[jn] = (f32x4){0.f, 0.f, 0.f, 0.f};
#pragma unroll
    for (int jn = 0; jn < 4; ++jn) {
        const int er = jn * 16 + fr;
        const bf16x8 vt0 = *(const bf16x8*)&Vt[er * 64 + ((((0 + fg) ^ (fr & 7))) << 3)];
        const bf16x8 vt1 = *(const bf16x8*)&Vt[er * 64 + ((((4 + fg) ^ (fr & 7))) << 3)];
        const bf16x8 tf0 = *(const bf16x8*)(pT + er * 64 + fg * 8);
        const bf16x8 tf1 = *(const bf16x8*)(pT + er * 64 + 32 + fg * 8);
        oacc[jn] = __builtin_amdgcn_mfma_f32_16x16x32_bf16(paf[0], vt0, oacc[jn], 0, 0, 0);
        oacc[jn] = __builtin_amdgcn_mfma_f32_16x16x32_bf16(paf[1], vt1, oacc[jn], 0, 0, 0);
        oacc[jn] = __builtin_amdgcn_mfma_f32_16x16x32_bf16(qf[0], tf0, oacc[jn], 0, 0, 0);
        oacc[jn] = __builtin_amdgcn_mfma_f32_16x16x32_bf16(qf[1], tf1, oacc[jn], 0, 0, 0);
    }

    // ---- epilogue: divide by den, store bf16 ----
#pragma unroll
    for (int r = 0; r < 4; ++r) {
        const int i = iw0 + fg * 4 + r;
        const float rcp = 1.0f / (denA[i] + rsA[i]);
        const size_t rowb = (size_t)(c * CHUNK + i) * DM + h * DH;
#pragma unroll
        for (int jn = 0; jn < 4; ++jn)
            out_pre[rowb + jn * 16 + fr] = bf16r(oacc[jn][r] * rcp);
    }
}

extern "C" void kernel_launch(void* const* d_in, const int* in_sizes, int n_in,
                              void* d_out, int out_size, void* d_ws, size_t ws_size,
                              hipStream_t stream)
{
    const float* x    = (const float*)d_in[0];
    const float* Wq   = (const float*)d_in[1];
    const float* bq   = (const float*)d_in[2];
    const float* Wk   = (const float*)d_in[3];
    const float* bk   = (const float*)d_in[4];
    const float* Wv   = (const float*)d_in[5];
    const float* bv   = (const float*)d_in[6];
    const float* Wo   = (const float*)d_in[7];
    const float* bo   = (const float*)d_in[8];
    const float* beta = (const float*)d_in[9];
    float* out = (float*)d_out;

    // workspace layout
    ushort* q_ws  = (ushort*)d_ws;                                 // 3 x 2M bf16 (q|k|v)
    ushort* k_ws  = q_ws + (size_t)NH * S_LEN * DH;
    ushort* v_ws  = k_ws + (size_t)NH * S_LEN * DH;
    float*  st    = (float*)(v_ws + (size_t)NH * S_LEN * DH);      // 16*32*4160 f32
    ushort* x_bf  = (ushort*)(st + (size_t)NH * NCH * ST_STRIDE);  // 2M bf16
    ushort* w_bf  = x_bf + (size_t)S_LEN * DM;                     // 4 x 1M bf16
    ushort* op_bf = w_bf + (size_t)4 * DM * DM;                    // 2M bf16
    ushort* pfxT  = op_bf + (size_t)S_LEN * DM;                    // 16*32*4160 bf16

    const ushort* wo_bf = w_bf + (size_t)3 * DM * DM;

    cast_all_kernel<<<dim3((DM * DM) / 1024, 6), 256, 0, stream>>>(x, Wq, Wk, Wv, Wo, x_bf, w_bf);

    qkv_gemm_kernel<<<768, 256, 0, stream>>>(x_bf, w_bf, bq, bk, bv, beta, q_ws);

    chunk_state_kernel<<<dim3(NCH, NH), 256, 0, stream>>>(k_ws, v_ws, st);
    scan_kernel<<<dim3(ST_STRIDE / 64, NH), 64, 0, stream>>>(st, pfxT);
    attn_out_kernel<<<dim3(NCH, NH), 256, 0, stream>>>(q_ws, k_ws, v_ws, st, pfxT, op_bf);

    o_gemm_kernel<<<512, 256, 0, stream>>>(op_bf, wo_bf, bo, out);
}